// Round 4
// baseline (230.365 us; speedup 1.0000x reference)
//
#include <hip/hip_runtime.h>

// SpikeFP32LayerNorm: LayerNorm (no affine) over rows of (8192, 4096) fp32,
// statistics + normalization in FP64 per the reference circuit:
//   mean = sum(x64)/N ; c = x64 - mean ; var = sum(c*c)/N ; vpe = var + 1e-6
//   y = 1/vpe ; 5x NR: y = 0.5*y*(3 - vpe*y*y) ; out = fp32(c * y)
//
// v5: v3 structure, CACHED LOADS + NONTEMPORAL STORES.
//   2x2 evidence: v3 (NT loads+stores) kernel ~57.5us; v4 (cached both)
//   79.8us with FETCH only 65.6MB (input is ~half L3-resident across bench
//   iterations!) but WRITE path regressed (L2 write-allocate + dirty-evict
//   thrash). Streaming-store pattern takes the good half of each:
//   - plain vec4 loads: exploit L3 residency of the 134MB input
//   - NT vec4 stores: no L2 write-allocate, stream to HBM like the fills
// Everything else bit-identical to v3/v4 (absmax 0.0).

#define LN_BATCH   8192
#define LN_N       4096
#define LN_THREADS 256            // 4 waves, one row at a time per block
#define LN_WAVES   4
#define LN_F4PT    4              // vec4 per lane: 16 elems/lane
#define LN_GRID    2048           // persistent blocks
#define LN_ROWS_PB (LN_BATCH / LN_GRID)   // 4 rows per block
#define LN_EPS     1e-6

typedef float vfloat4 __attribute__((ext_vector_type(4)));

__device__ __forceinline__ double wave_allreduce_add(double s) {
#pragma unroll
    for (int off = 1; off < 64; off <<= 1)
        s += __shfl_xor(s, off, 64);
    return s;
}

__global__ __launch_bounds__(LN_THREADS, 7)
void spike_layernorm_kernel(const float* __restrict__ x, float* __restrict__ out) {
    const int wave = threadIdx.x >> 6;
    const int lane = threadIdx.x & 63;
    // vec4 index within the row: each wave owns a contiguous quarter (256 vec4)
    const int vbase = wave * (LN_N / 4 / LN_WAVES) + lane;

    __shared__ double red[2][LN_WAVES];

    // Prologue: load row blockIdx.x (plain cached loads -> L3 hits)
    vfloat4 v[LN_F4PT];
    {
        const vfloat4* __restrict__ xr =
            reinterpret_cast<const vfloat4*>(x + (size_t)blockIdx.x * LN_N);
#pragma unroll
        for (int i = 0; i < LN_F4PT; ++i)
            v[i] = xr[vbase + i * 64];
    }

#pragma unroll
    for (int it = 0; it < LN_ROWS_PB; ++it) {
        const int r = blockIdx.x + it * LN_GRID;

        // ---- Prefetch row r+LN_GRID (plain cached loads) ----
        vfloat4 w[LN_F4PT];
        if (it + 1 < LN_ROWS_PB) {
            const vfloat4* __restrict__ xn =
                reinterpret_cast<const vfloat4*>(x + (size_t)(r + LN_GRID) * LN_N);
#pragma unroll
            for (int i = 0; i < LN_F4PT; ++i)
                w[i] = xn[vbase + i * 64];
        }

        // ---- Pass 1: FP64 sum -> mean ----
        double s0 = 0.0, s1 = 0.0;
#pragma unroll
        for (int i = 0; i < LN_F4PT; ++i) {
            s0 += (double)v[i].x + (double)v[i].y;
            s1 += (double)v[i].z + (double)v[i].w;
        }
        double s = wave_allreduce_add(s0 + s1);
        if (lane == 0) red[0][wave] = s;
        __syncthreads();
        const double mean =
            ((red[0][0] + red[0][1]) + (red[0][2] + red[0][3])) * (1.0 / LN_N);

        // ---- Pass 2: FP64 sum of (x-mean)^2 -> var ----
        double q0 = 0.0, q1 = 0.0;
#pragma unroll
        for (int i = 0; i < LN_F4PT; ++i) {
            double d;
            d = (double)v[i].x - mean; q0 += d * d;
            d = (double)v[i].y - mean; q1 += d * d;
            d = (double)v[i].z - mean; q0 += d * d;
            d = (double)v[i].w - mean; q1 += d * d;
        }
        double q = wave_allreduce_add(q0 + q1);
        if (lane == 0) red[1][wave] = q;
        __syncthreads();
        const double var =
            ((red[1][0] + red[1][1]) + (red[1][2] + red[1][3])) * (1.0 / LN_N);

        // ---- NR reciprocal refinement (wave-uniform on all lanes) ----
        const double vpe = var + LN_EPS;
        double y = 1.0 / vpe;
#pragma unroll
        for (int nr = 0; nr < 5; ++nr)
            y = 0.5 * y * (3.0 - vpe * (y * y));

        // ---- Pass 3: out = fp32((x64 - mean) * y), NT streaming stores ----
        vfloat4* __restrict__ orow =
            reinterpret_cast<vfloat4*>(out + (size_t)r * LN_N);
#pragma unroll
        for (int i = 0; i < LN_F4PT; ++i) {
            vfloat4 o;
            o.x = (float)(((double)v[i].x - mean) * y);
            o.y = (float)(((double)v[i].y - mean) * y);
            o.z = (float)(((double)v[i].z - mean) * y);
            o.w = (float)(((double)v[i].w - mean) * y);
            __builtin_nontemporal_store(o, &orow[vbase + i * 64]);
        }

        // Rotate prefetched row into place (SSA-renamed, no real moves).
        if (it + 1 < LN_ROWS_PB) {
#pragma unroll
            for (int i = 0; i < LN_F4PT; ++i) v[i] = w[i];
        }
    }
}

extern "C" void kernel_launch(void* const* d_in, const int* in_sizes, int n_in,
                              void* d_out, int out_size, void* d_ws, size_t ws_size,
                              hipStream_t stream) {
    const float* x = (const float*)d_in[0];
    float* out = (float*)d_out;
    spike_layernorm_kernel<<<LN_GRID, LN_THREADS, 0, stream>>>(x, out);
}

// Round 5
// 217.767 us; speedup vs baseline: 1.0579x; 1.0579x over previous
//
#include <hip/hip_runtime.h>

// SpikeFP32LayerNorm: LayerNorm (no affine) over rows of (8192, 4096) fp32,
// statistics + normalization in FP64 per the reference circuit:
//   mean = sum(x64)/N ; c = x64 - mean ; var = sum(c*c)/N ; vpe = var + 1e-6
//   y = 1/vpe ; 5x NR: y = 0.5*y*(3 - vpe*y*y) ; out = fp32(c * y)
//
// v6: v3 structure, NT LOADS + PLAIN CACHED STORES (last cell of the 2x2).
//   Measured: v3(NT/NT)=57.5us, v4(C/C)=79.8, v5(C/NT)=79.8.
//   v4==v5 -> with cached loads, store policy irrelevant; cached LOADS are
//   the slow path. The two fast regimes on this chip both use cached
//   stores: harness fill 6.76 TB/s (plain stores, 9.5% occupancy) and m13
//   copy 6.29 TB/s. Theory: NT loads keep L2 clean (no read-line installs),
//   cached stores then get full L2 write staging/combining -> fill-quality
//   bursts to HBM. NT stores (v3) forfeit that staging.
// Everything else bit-identical to v3 (absmax 0.0).

#define LN_BATCH   8192
#define LN_N       4096
#define LN_THREADS 256            // 4 waves, one row at a time per block
#define LN_WAVES   4
#define LN_F4PT    4              // vec4 per lane: 16 elems/lane
#define LN_GRID    2048           // persistent blocks
#define LN_ROWS_PB (LN_BATCH / LN_GRID)   // 4 rows per block
#define LN_EPS     1e-6

typedef float vfloat4 __attribute__((ext_vector_type(4)));

__device__ __forceinline__ double wave_allreduce_add(double s) {
#pragma unroll
    for (int off = 1; off < 64; off <<= 1)
        s += __shfl_xor(s, off, 64);
    return s;
}

__global__ __launch_bounds__(LN_THREADS, 7)
void spike_layernorm_kernel(const float* __restrict__ x, float* __restrict__ out) {
    const int wave = threadIdx.x >> 6;
    const int lane = threadIdx.x & 63;
    // vec4 index within the row: each wave owns a contiguous quarter (256 vec4)
    const int vbase = wave * (LN_N / 4 / LN_WAVES) + lane;

    __shared__ double red[2][LN_WAVES];

    // Prologue: load row blockIdx.x (NT loads: no L1/L2 allocation)
    vfloat4 v[LN_F4PT];
    {
        const vfloat4* __restrict__ xr =
            reinterpret_cast<const vfloat4*>(x + (size_t)blockIdx.x * LN_N);
#pragma unroll
        for (int i = 0; i < LN_F4PT; ++i)
            v[i] = __builtin_nontemporal_load(&xr[vbase + i * 64]);
    }

#pragma unroll
    for (int it = 0; it < LN_ROWS_PB; ++it) {
        const int r = blockIdx.x + it * LN_GRID;

        // ---- Prefetch row r+LN_GRID (NT loads, in flight across compute) ----
        vfloat4 w[LN_F4PT];
        if (it + 1 < LN_ROWS_PB) {
            const vfloat4* __restrict__ xn =
                reinterpret_cast<const vfloat4*>(x + (size_t)(r + LN_GRID) * LN_N);
#pragma unroll
            for (int i = 0; i < LN_F4PT; ++i)
                w[i] = __builtin_nontemporal_load(&xn[vbase + i * 64]);
        }

        // ---- Pass 1: FP64 sum -> mean ----
        double s0 = 0.0, s1 = 0.0;
#pragma unroll
        for (int i = 0; i < LN_F4PT; ++i) {
            s0 += (double)v[i].x + (double)v[i].y;
            s1 += (double)v[i].z + (double)v[i].w;
        }
        double s = wave_allreduce_add(s0 + s1);
        if (lane == 0) red[0][wave] = s;
        __syncthreads();
        const double mean =
            ((red[0][0] + red[0][1]) + (red[0][2] + red[0][3])) * (1.0 / LN_N);

        // ---- Pass 2: FP64 sum of (x-mean)^2 -> var ----
        double q0 = 0.0, q1 = 0.0;
#pragma unroll
        for (int i = 0; i < LN_F4PT; ++i) {
            double d;
            d = (double)v[i].x - mean; q0 += d * d;
            d = (double)v[i].y - mean; q1 += d * d;
            d = (double)v[i].z - mean; q0 += d * d;
            d = (double)v[i].w - mean; q1 += d * d;
        }
        double q = wave_allreduce_add(q0 + q1);
        if (lane == 0) red[1][wave] = q;
        __syncthreads();
        const double var =
            ((red[1][0] + red[1][1]) + (red[1][2] + red[1][3])) * (1.0 / LN_N);

        // ---- NR reciprocal refinement (wave-uniform on all lanes) ----
        const double vpe = var + LN_EPS;
        double y = 1.0 / vpe;
#pragma unroll
        for (int nr = 0; nr < 5; ++nr)
            y = 0.5 * y * (3.0 - vpe * (y * y));

        // ---- Pass 3: out = fp32((x64 - mean) * y), PLAIN cached stores ----
        vfloat4* __restrict__ orow =
            reinterpret_cast<vfloat4*>(out + (size_t)r * LN_N);
#pragma unroll
        for (int i = 0; i < LN_F4PT; ++i) {
            vfloat4 o;
            o.x = (float)(((double)v[i].x - mean) * y);
            o.y = (float)(((double)v[i].y - mean) * y);
            o.z = (float)(((double)v[i].z - mean) * y);
            o.w = (float)(((double)v[i].w - mean) * y);
            orow[vbase + i * 64] = o;
        }

        // Rotate prefetched row into place (SSA-renamed, no real moves).
        if (it + 1 < LN_ROWS_PB) {
#pragma unroll
            for (int i = 0; i < LN_F4PT; ++i) v[i] = w[i];
        }
    }
}

extern "C" void kernel_launch(void* const* d_in, const int* in_sizes, int n_in,
                              void* d_out, int out_size, void* d_ws, size_t ws_size,
                              hipStream_t stream) {
    const float* x = (const float*)d_in[0];
    float* out = (float*)d_out;
    spike_layernorm_kernel<<<LN_GRID, LN_THREADS, 0, stream>>>(x, out);
}